// Round 1
// baseline (520.728 us; speedup 1.0000x reference)
//
#include <hip/hip_runtime.h>
#include <stdint.h>

#define G_ 8
#define S_ 16
#define H_ 512
#define TB 128
#define NTH 512

typedef _Float16 h16;
typedef _Float16 h16x8 __attribute__((ext_vector_type(8)));
typedef _Float16 h16x4 __attribute__((ext_vector_type(4)));
typedef float f32x4 __attribute__((ext_vector_type(4)));

#define XB_STRIDE 40                      // h16 units per xb row (80 B, 16B-aligned, bank-spread)
#define HB_BYTES (TB * 1024)              // 128 rows x 512 h16 = 128 KB
#define SMEM_BYTES (HB_BYTES + TB * XB_STRIDE * 2)

__device__ __forceinline__ float swishf(float v, float sp) {
    return v * (1.0f / (1.0f + __expf(-v * sp))) * (1.0f / 1.1f);
}

// B-fragment loader: n-row `row`, k-offset `k`. USEWS: fp16 pre-converted (strideH).
// Fallback: fp32 weights, convert inline; k >= strideF is the zero-pad region (W1 only).
template<bool USEWS>
__device__ __forceinline__ h16x8 loadB(const h16* __restrict__ wh,
                                       const float* __restrict__ wf,
                                       int row, int k, int strideH, int strideF) {
    if constexpr (USEWS) {
        return *(const h16x8*)(wh + (size_t)row * strideH + k);
    } else {
        h16x8 r;
        if (k < strideF) {
            const float* p = wf + (size_t)row * strideF + k;
            #pragma unroll
            for (int j = 0; j < 8; ++j) r[j] = (h16)p[j];
        } else {
            #pragma unroll
            for (int j = 0; j < 8; ++j) r[j] = (h16)0.f;
        }
        return r;
    }
}

// swizzled byte offset into hbuf: row stride 1024B, XOR bits 4-6 with row&7
__device__ __forceinline__ uint32_t hswz(int row, uint32_t byte_in_row) {
    return (uint32_t)row * 1024u + (byte_in_row ^ (((uint32_t)(row & 7)) << 4));
}

__device__ __forceinline__ void swish_store(const f32x4 (&acc)[8][4], char* hb,
                                            const float* __restrict__ bias, float sp,
                                            int wc0, int l15, int lq) {
    #pragma unroll
    for (int nt = 0; nt < 4; ++nt) {
        const int col = wc0 + nt * 16 + l15;
        const float bv = bias[col];
        #pragma unroll
        for (int mt = 0; mt < 8; ++mt) {
            #pragma unroll
            for (int r = 0; r < 4; ++r) {
                const int row = mt * 16 + lq * 4 + r;
                const float v = acc[mt][nt][r] + bv;
                *(h16*)(hb + hswz(row, (uint32_t)(col * 2))) = (h16)swishf(v, sp);
            }
        }
    }
}

// One H->H layer: C[128x512] = A(hbuf) * W^T, wave owns 64-col slice, K=512
template<bool USEWS>
__device__ __forceinline__ void layerH(f32x4 (&acc)[8][4],
                                       const h16* __restrict__ wh, const float* __restrict__ wf,
                                       const char* __restrict__ hb, int wc0, int l15, int lq) {
    #pragma unroll
    for (int mt = 0; mt < 8; ++mt)
        #pragma unroll
        for (int nt = 0; nt < 4; ++nt) acc[mt][nt] = (f32x4){0.f, 0.f, 0.f, 0.f};

    h16x8 bfr[4];
    #pragma unroll
    for (int nt = 0; nt < 4; ++nt)
        bfr[nt] = loadB<USEWS>(wh, wf, wc0 + nt * 16 + l15, lq * 8, H_, H_);

    #pragma unroll 4
    for (int k0 = 0; k0 < H_; k0 += 32) {
        h16x8 bnx[4];
        const int kn = (k0 + 32 < H_) ? (k0 + 32) : 0;  // clamped prefetch (last iter dummy)
        #pragma unroll
        for (int nt = 0; nt < 4; ++nt)
            bnx[nt] = loadB<USEWS>(wh, wf, wc0 + nt * 16 + l15, kn + lq * 8, H_, H_);
        #pragma unroll
        for (int mt = 0; mt < 8; ++mt) {
            const int row = mt * 16 + l15;
            const h16x8 a = *(const h16x8*)(hb + hswz(row, (uint32_t)(k0 * 2 + lq * 16)));
            #pragma unroll
            for (int nt = 0; nt < 4; ++nt)
                acc[mt][nt] = __builtin_amdgcn_mfma_f32_16x16x32_f16(a, bfr[nt], acc[mt][nt], 0, 0, 0);
        }
        #pragma unroll
        for (int nt = 0; nt < 4; ++nt) bfr[nt] = bnx[nt];
    }
}

template<bool USEWS>
__global__ __launch_bounds__(NTH, 2) void mlp_fused(
    const float* __restrict__ x,
    const float* __restrict__ W1f, const float* __restrict__ b1, const float* __restrict__ be1,
    const float* __restrict__ W2f, const float* __restrict__ b2, const float* __restrict__ be2,
    const float* __restrict__ W3f, const float* __restrict__ b3, const float* __restrict__ be3,
    const float* __restrict__ W4f, const float* __restrict__ b4,
    const h16* __restrict__ W1h, const h16* __restrict__ W2h,
    const h16* __restrict__ W3h, const h16* __restrict__ W4h,
    float* __restrict__ out) {
    extern __shared__ char smem[];
    h16* __restrict__ xb = (h16*)(smem + HB_BYTES);

    const int bid = blockIdx.x;
    const int g = bid & 7;                 // group fastest -> XCD i%8 sees one group's weights
    const int rowbase = (bid >> 3) * TB;
    const int tid = threadIdx.x;
    const int wv = tid >> 6;
    const int ln = tid & 63;
    const int l15 = ln & 15;
    const int lq = ln >> 4;
    const int wc0 = wv * 64;

    const float sp1 = log1pf(__expf(be1[g]));
    const float sp2 = log1pf(__expf(be2[g]));
    const float sp3 = log1pf(__expf(be3[g]));

    // stage x tile -> fp16, K padded 16->32 with zeros
    for (int i = tid; i < TB * S_; i += NTH) {
        const int r = i >> 4, s = i & 15;
        const float v = x[(size_t)(rowbase + r) * (G_ * S_) + g * S_ + s];
        xb[r * XB_STRIDE + s] = (h16)v;
        xb[r * XB_STRIDE + 16 + s] = (h16)0.f;
    }
    __syncthreads();

    f32x4 acc[8][4];

    // ---- layer 1: [128,16(->32)] x W1[512,16]^T ----
    {
        #pragma unroll
        for (int mt = 0; mt < 8; ++mt)
            #pragma unroll
            for (int nt = 0; nt < 4; ++nt) acc[mt][nt] = (f32x4){0.f, 0.f, 0.f, 0.f};
        h16x8 bfr[4];
        #pragma unroll
        for (int nt = 0; nt < 4; ++nt)
            bfr[nt] = loadB<USEWS>(W1h + (size_t)g * H_ * 32, W1f + (size_t)g * H_ * S_,
                                   wc0 + nt * 16 + l15, lq * 8, 32, S_);
        #pragma unroll
        for (int mt = 0; mt < 8; ++mt) {
            const h16x8 a = *(const h16x8*)(xb + (mt * 16 + l15) * XB_STRIDE + lq * 8);
            #pragma unroll
            for (int nt = 0; nt < 4; ++nt)
                acc[mt][nt] = __builtin_amdgcn_mfma_f32_16x16x32_f16(a, bfr[nt], acc[mt][nt], 0, 0, 0);
        }
    }
    swish_store(acc, smem, b1 + g * H_, sp1, wc0, l15, lq);
    __syncthreads();

    // ---- layer 2 ----
    layerH<USEWS>(acc, W2h + (size_t)g * H_ * H_, W2f + (size_t)g * H_ * H_, smem, wc0, l15, lq);
    __syncthreads();   // everyone done reading hbuf
    swish_store(acc, smem, b2 + g * H_, sp2, wc0, l15, lq);
    __syncthreads();

    // ---- layer 3 ----
    layerH<USEWS>(acc, W3h + (size_t)g * H_ * H_, W3f + (size_t)g * H_ * H_, smem, wc0, l15, lq);
    __syncthreads();
    swish_store(acc, smem, b3 + g * H_, sp3, wc0, l15, lq);
    __syncthreads();

    // ---- layer 4: out[128,16] = h3 x W4[16,512]^T ; wave w owns m-tile w ----
    {
        f32x4 a4 = {0.f, 0.f, 0.f, 0.f};
        const h16* w4h = W4h + (size_t)g * S_ * H_;
        const float* w4f = W4f + (size_t)g * S_ * H_;
        const int arow = wv * 16 + l15;
        #pragma unroll 4
        for (int k0 = 0; k0 < H_; k0 += 32) {
            const h16x8 a = *(const h16x8*)(smem + hswz(arow, (uint32_t)(k0 * 2 + lq * 16)));
            const h16x8 b = loadB<USEWS>(w4h, w4f, l15, k0 + lq * 8, H_, H_);
            a4 = __builtin_amdgcn_mfma_f32_16x16x32_f16(a, b, a4, 0, 0, 0);
        }
        const float bv = b4[g * S_ + l15];
        #pragma unroll
        for (int r = 0; r < 4; ++r)
            out[(size_t)(rowbase + wv * 16 + lq * 4 + r) * (G_ * S_) + g * S_ + l15] = a4[r] + bv;
    }
}

// ---- weight conversion prologue kernels ----
__global__ void cvt4(const float* __restrict__ s, h16* __restrict__ d, int n) {
    const int i = (blockIdx.x * blockDim.x + threadIdx.x) * 4;
    if (i < n) {
        const float4 v = *(const float4*)(s + i);
        h16x4 o;
        o[0] = (h16)v.x; o[1] = (h16)v.y; o[2] = (h16)v.z; o[3] = (h16)v.w;
        *(h16x4*)(d + i) = o;
    }
}

__global__ void cvtW1(const float* __restrict__ s, h16* __restrict__ d) {
    const int row = blockIdx.x * blockDim.x + threadIdx.x;   // 8*512 rows
    if (row < G_ * H_) {
        const float* sp = s + (size_t)row * S_;
        h16* dp = d + (size_t)row * 32;
        #pragma unroll
        for (int j = 0; j < 16; ++j) dp[j] = (h16)sp[j];
        #pragma unroll
        for (int j = 16; j < 32; ++j) dp[j] = (h16)0.f;
    }
}

extern "C" void kernel_launch(void* const* d_in, const int* in_sizes, int n_in,
                              void* d_out, int out_size, void* d_ws, size_t ws_size,
                              hipStream_t stream) {
    const float* x   = (const float*)d_in[0];
    const float* W1  = (const float*)d_in[1];
    const float* b1  = (const float*)d_in[2];
    const float* be1 = (const float*)d_in[3];
    const float* W2  = (const float*)d_in[4];
    const float* b2  = (const float*)d_in[5];
    const float* be2 = (const float*)d_in[6];
    const float* W3  = (const float*)d_in[7];
    const float* b3  = (const float*)d_in[8];
    const float* be3 = (const float*)d_in[9];
    const float* W4  = (const float*)d_in[10];
    const float* b4  = (const float*)d_in[11];
    float* out = (float*)d_out;

    const size_t nW2  = (size_t)G_ * H_ * H_;   // 2097152
    const size_t nW1h = (size_t)G_ * H_ * 32;   // 131072 (padded)
    const size_t nW4  = (size_t)G_ * S_ * H_;   // 65536
    const size_t need = (2 * nW2 + nW1h + nW4) * sizeof(h16);

    const dim3 grid(1024), blk(NTH);

    if (ws_size >= need) {
        h16* W2h = (h16*)d_ws;
        h16* W3h = W2h + nW2;
        h16* W1h = W3h + nW2;
        h16* W4h = W1h + nW1h;
        cvt4<<<dim3((unsigned)(nW2 / 4 / 256)), dim3(256), 0, stream>>>(W2, W2h, (int)nW2);
        cvt4<<<dim3((unsigned)(nW2 / 4 / 256)), dim3(256), 0, stream>>>(W3, W3h, (int)nW2);
        cvt4<<<dim3((unsigned)(nW4 / 4 / 256)), dim3(256), 0, stream>>>(W4, W4h, (int)nW4);
        cvtW1<<<dim3(16), dim3(256), 0, stream>>>(W1, W1h);
        (void)hipFuncSetAttribute(reinterpret_cast<const void*>(mlp_fused<true>),
                                  hipFuncAttributeMaxDynamicSharedMemorySize, (int)SMEM_BYTES);
        mlp_fused<true><<<grid, blk, SMEM_BYTES, stream>>>(
            x, W1, b1, be1, W2, b2, be2, W3, b3, be3, W4, b4,
            W1h, W2h, W3h, W4h, out);
    } else {
        // ws too small: read fp32 weights directly, convert inline (slower, still correct)
        (void)hipFuncSetAttribute(reinterpret_cast<const void*>(mlp_fused<false>),
                                  hipFuncAttributeMaxDynamicSharedMemorySize, (int)SMEM_BYTES);
        mlp_fused<false><<<grid, blk, SMEM_BYTES, stream>>>(
            x, W1, b1, be1, W2, b2, be2, W3, b3, be3, W4, b4,
            nullptr, nullptr, nullptr, nullptr, out);
    }
}

// Round 2
// 218.613 us; speedup vs baseline: 2.3820x; 2.3820x over previous
//
#include <hip/hip_runtime.h>
#include <stdint.h>

#define G_ 8
#define S_ 16
#define H_ 512
#define TB 128
#define NTH 1024

typedef _Float16 h16;
typedef _Float16 h16x8 __attribute__((ext_vector_type(8)));
typedef float f32x4 __attribute__((ext_vector_type(4)));

#define XB_STRIDE 40                      // h16 units per xb row (80 B, bank-spread)
#define HB_BYTES (TB * 1024)              // 128 rows x 512 h16 = 128 KB
#define SMEM_BYTES (HB_BYTES + TB * XB_STRIDE * 2)

__device__ __forceinline__ float swishf(float v, float sp) {
    const float e = __expf(-v * sp);
    return v * __builtin_amdgcn_rcpf(1.0f + e) * (1.0f / 1.1f);
}

// swizzled byte offset into hbuf: row stride 1024B, XOR bits 4-6 with row&7
__device__ __forceinline__ uint32_t hswz(int row, uint32_t byte_in_row) {
    return (uint32_t)row * 1024u + (byte_in_row ^ (((uint32_t)(row & 7)) << 4));
}

// B fragment: packed layout [colBlk][kBlk=K/32][64 lanes][8 h16] -> one coalesced 16B/lane read.
// Fallback (USEWS=false): gather from fp32 row-major W[N][Ksrc]; k >= Ksrc reads 0 (W1 pad).
template<bool USEWS>
__device__ __forceinline__ h16x8 loadBfrag(const h16* __restrict__ wpk,
                                           const float* __restrict__ wf,
                                           int colBlk, int k0, int ln, int K, int Ksrc) {
    if constexpr (USEWS) {
        return *(const h16x8*)(wpk + ((size_t)colBlk * (K >> 5) + (k0 >> 5)) * 512 + ln * 8);
    } else {
        const int row = colBlk * 16 + (ln & 15);
        const int k = k0 + (ln >> 4) * 8;
        h16x8 r;
        if (k < Ksrc) {
            const float* p = wf + (size_t)row * Ksrc + k;
            #pragma unroll
            for (int j = 0; j < 8; ++j) r[j] = (h16)p[j];
        } else {
            #pragma unroll
            for (int j = 0; j < 8; ++j) r[j] = (h16)0.f;
        }
        return r;
    }
}

// swish + bias, then pack pairs of adjacent cols via shfl_xor(1) -> ds_write_b32
__device__ __forceinline__ void swish_store(const f32x4 (&acc)[4][4], char* hb,
                                            const float* __restrict__ bias, float sp,
                                            int mbase, int wc0, int ln) {
    const int l15 = ln & 15, lq = ln >> 4, pe = l15 & 1;
    #pragma unroll
    for (int nt = 0; nt < 4; ++nt) {
        const int col = wc0 + nt * 16 + l15;
        const float bv = bias[col];
        const uint32_t cb2 = (uint32_t)((col & ~1) * 2);   // byte offset of even col of pair
        #pragma unroll
        for (int mt = 0; mt < 4; ++mt) {
            float v[4], t[4];
            #pragma unroll
            for (int r = 0; r < 4; ++r) v[r] = swishf(acc[mt][nt][r] + bv, sp);
            #pragma unroll
            for (int r = 0; r < 4; ++r) t[r] = __shfl_xor(v[r], 1);
            const int rowb = mbase + mt * 16 + lq * 4 + 2 * pe;
            #pragma unroll
            for (int q = 0; q < 2; ++q) {
                const float a0 = pe ? t[2 + q] : v[q];     // even col value, row rowb+q
                const float a1 = pe ? v[2 + q] : t[q];     // odd col value
                union { h16 h[2]; uint32_t u; } pk;
                pk.h[0] = (h16)a0; pk.h[1] = (h16)a1;
                *(uint32_t*)(hb + hswz(rowb + q, cb2)) = pk.u;
            }
        }
    }
}

// One H->H layer: wave computes 64x64 tile, K=512, B direct from global (packed frags)
template<bool USEWS>
__device__ __forceinline__ void layerH(f32x4 (&acc)[4][4],
                                       const h16* __restrict__ wpk, const float* __restrict__ wf,
                                       const char* __restrict__ hb, int mbase, int wc0, int ln) {
    const int l15 = ln & 15, lq = ln >> 4;
    const int cB = wc0 >> 4;
    #pragma unroll
    for (int mt = 0; mt < 4; ++mt)
        #pragma unroll
        for (int nt = 0; nt < 4; ++nt) acc[mt][nt] = (f32x4){0.f, 0.f, 0.f, 0.f};

    h16x8 bfr[4];
    #pragma unroll
    for (int nt = 0; nt < 4; ++nt)
        bfr[nt] = loadBfrag<USEWS>(wpk, wf, cB + nt, 0, ln, H_, H_);

    #pragma unroll 2
    for (int k0 = 0; k0 < H_; k0 += 32) {
        h16x8 bnx[4];
        const int kn = (k0 + 32 < H_) ? (k0 + 32) : 0;   // clamped prefetch (last iter dummy)
        #pragma unroll
        for (int nt = 0; nt < 4; ++nt)
            bnx[nt] = loadBfrag<USEWS>(wpk, wf, cB + nt, kn, ln, H_, H_);
        #pragma unroll
        for (int mt = 0; mt < 4; ++mt) {
            const h16x8 a = *(const h16x8*)(hb + hswz(mbase + mt * 16 + l15,
                                                      (uint32_t)(k0 * 2 + lq * 16)));
            #pragma unroll
            for (int nt = 0; nt < 4; ++nt)
                acc[mt][nt] = __builtin_amdgcn_mfma_f32_16x16x32_f16(a, bfr[nt], acc[mt][nt], 0, 0, 0);
        }
        #pragma unroll
        for (int nt = 0; nt < 4; ++nt) bfr[nt] = bnx[nt];
    }
}

template<bool USEWS>
__global__ __launch_bounds__(NTH, 4) void mlp_fused(
    const float* __restrict__ x,
    const float* __restrict__ W1f, const float* __restrict__ b1, const float* __restrict__ be1,
    const float* __restrict__ W2f, const float* __restrict__ b2, const float* __restrict__ be2,
    const float* __restrict__ W3f, const float* __restrict__ b3, const float* __restrict__ be3,
    const float* __restrict__ W4f, const float* __restrict__ b4,
    const h16* __restrict__ W1p, const h16* __restrict__ W2p,
    const h16* __restrict__ W3p, const h16* __restrict__ W4p,
    float* __restrict__ out) {
    extern __shared__ char smem[];
    h16* __restrict__ xb = (h16*)(smem + HB_BYTES);

    const int bid = blockIdx.x;
    const int g = bid & 7;                 // group == XCD (blocks round-robin XCDs)
    const int rowbase = (bid >> 3) * TB;
    const int tid = threadIdx.x;
    const int wv = tid >> 6;
    const int ln = tid & 63;
    const int l15 = ln & 15;
    const int lq = ln >> 4;
    const int mbase = (wv >> 3) * 64;      // 2 wave-rows x 8 wave-cols over [128][512]
    const int wc0 = (wv & 7) * 64;

    const float sp1 = log1pf(__expf(be1[g]));
    const float sp2 = log1pf(__expf(be2[g]));
    const float sp3 = log1pf(__expf(be3[g]));

    const h16* w1p = W1p + (size_t)g * H_ * 32;
    const h16* w2p = W2p + (size_t)g * H_ * H_;
    const h16* w3p = W3p + (size_t)g * H_ * H_;
    const h16* w4p = W4p + (size_t)g * S_ * H_;
    const float* w1f = W1f + (size_t)g * H_ * S_;
    const float* w2f = W2f + (size_t)g * H_ * H_;
    const float* w3f = W3f + (size_t)g * H_ * H_;
    const float* w4f = W4f + (size_t)g * S_ * H_;

    // stage x tile -> fp16, K padded 16->32 with zeros
    for (int i = tid; i < TB * S_; i += NTH) {
        const int r = i >> 4, s = i & 15;
        const float v = x[(size_t)(rowbase + r) * (G_ * S_) + g * S_ + s];
        xb[r * XB_STRIDE + s] = (h16)v;
        xb[r * XB_STRIDE + 16 + s] = (h16)0.f;
    }
    __syncthreads();

    f32x4 acc[4][4];

    // ---- layer 1: [128,16(->32)] x W1[512,16]^T, single K-step ----
    {
        #pragma unroll
        for (int mt = 0; mt < 4; ++mt)
            #pragma unroll
            for (int nt = 0; nt < 4; ++nt) acc[mt][nt] = (f32x4){0.f, 0.f, 0.f, 0.f};
        h16x8 bfr[4];
        #pragma unroll
        for (int nt = 0; nt < 4; ++nt)
            bfr[nt] = loadBfrag<USEWS>(w1p, w1f, (wc0 >> 4) + nt, 0, ln, 32, S_);
        #pragma unroll
        for (int mt = 0; mt < 4; ++mt) {
            const h16x8 a = *(const h16x8*)(xb + (mbase + mt * 16 + l15) * XB_STRIDE + lq * 8);
            #pragma unroll
            for (int nt = 0; nt < 4; ++nt)
                acc[mt][nt] = __builtin_amdgcn_mfma_f32_16x16x32_f16(a, bfr[nt], acc[mt][nt], 0, 0, 0);
        }
    }
    swish_store(acc, smem, b1 + g * H_, sp1, mbase, wc0, ln);
    __syncthreads();

    // ---- layer 2 ----
    layerH<USEWS>(acc, w2p, w2f, smem, mbase, wc0, ln);
    __syncthreads();                       // all hbuf reads done
    swish_store(acc, smem, b2 + g * H_, sp2, mbase, wc0, ln);
    __syncthreads();

    // ---- layer 3 ----
    layerH<USEWS>(acc, w3p, w3f, smem, mbase, wc0, ln);
    __syncthreads();
    swish_store(acc, smem, b3 + g * H_, sp3, mbase, wc0, ln);
    __syncthreads();

    // ---- layer 4: out[128,16] = h3 x W4[16,512]^T ; waves 0..7 own 16-row m-tiles ----
    if (wv < 8) {
        f32x4 a4 = {0.f, 0.f, 0.f, 0.f};
        #pragma unroll 2
        for (int k0 = 0; k0 < H_; k0 += 32) {
            const h16x8 a = *(const h16x8*)(smem + hswz(wv * 16 + l15,
                                                        (uint32_t)(k0 * 2 + lq * 16)));
            const h16x8 b = loadBfrag<USEWS>(w4p, w4f, 0, k0, ln, H_, H_);
            a4 = __builtin_amdgcn_mfma_f32_16x16x32_f16(a, b, a4, 0, 0, 0);
        }
        const float bv = b4[g * S_ + l15];
        #pragma unroll
        for (int r = 0; r < 4; ++r)
            out[(size_t)(rowbase + wv * 16 + lq * 4 + r) * (G_ * S_) + g * S_ + l15] = a4[r] + bv;
    }
}

// ---- weight repack: fp32 [N][Ks] -> fp16 MFMA-fragment blocks [N/16][Kd/32][64][8] ----
__global__ void packW(const float* __restrict__ s, h16* __restrict__ d,
                      int N, int Kd, int Ks) {
    const int t = blockIdx.x * 256 + threadIdx.x;
    const int total = (N * Kd) >> 3;
    if (t >= total) return;
    const int ln = t & 63;
    const int blk = t >> 6;
    const int kblocks = Kd >> 5;
    const int kb = blk % kblocks;
    const int nb = blk / kblocks;
    const int row = nb * 16 + (ln & 15);
    const int k = kb * 32 + (ln >> 4) * 8;
    h16x8 o;
    #pragma unroll
    for (int j = 0; j < 8; ++j)
        o[j] = (h16)((k + j < Ks) ? s[(size_t)row * Ks + k + j] : 0.f);
    *(h16x8*)(d + (size_t)t * 8) = o;
}

extern "C" void kernel_launch(void* const* d_in, const int* in_sizes, int n_in,
                              void* d_out, int out_size, void* d_ws, size_t ws_size,
                              hipStream_t stream) {
    const float* x   = (const float*)d_in[0];
    const float* W1  = (const float*)d_in[1];
    const float* b1  = (const float*)d_in[2];
    const float* be1 = (const float*)d_in[3];
    const float* W2  = (const float*)d_in[4];
    const float* b2  = (const float*)d_in[5];
    const float* be2 = (const float*)d_in[6];
    const float* W3  = (const float*)d_in[7];
    const float* b3  = (const float*)d_in[8];
    const float* be3 = (const float*)d_in[9];
    const float* W4  = (const float*)d_in[10];
    const float* b4  = (const float*)d_in[11];
    float* out = (float*)d_out;

    const size_t nW2  = (size_t)G_ * H_ * H_;   // 2097152
    const size_t nW1p = (size_t)G_ * H_ * 32;   // 131072 (K padded 16->32)
    const size_t nW4  = (size_t)G_ * S_ * H_;   // 65536
    const size_t need = (2 * nW2 + nW1p + nW4) * sizeof(h16);

    const dim3 grid(1024), blk(NTH);

    if (ws_size >= need) {
        h16* W2p = (h16*)d_ws;
        h16* W3p = W2p + nW2;
        h16* W1p = W3p + nW2;
        h16* W4p = W1p + nW1p;
        packW<<<dim3((unsigned)((nW2 / 8 + 255) / 256)), dim3(256), 0, stream>>>(W2, W2p, G_ * H_, H_, H_);
        packW<<<dim3((unsigned)((nW2 / 8 + 255) / 256)), dim3(256), 0, stream>>>(W3, W3p, G_ * H_, H_, H_);
        packW<<<dim3((unsigned)((nW4 / 8 + 255) / 256)), dim3(256), 0, stream>>>(W4, W4p, G_ * S_, H_, H_);
        packW<<<dim3((unsigned)((nW1p / 8 + 255) / 256)), dim3(256), 0, stream>>>(W1, W1p, G_ * H_, 32, S_);
        (void)hipFuncSetAttribute(reinterpret_cast<const void*>(mlp_fused<true>),
                                  hipFuncAttributeMaxDynamicSharedMemorySize, (int)SMEM_BYTES);
        mlp_fused<true><<<grid, blk, SMEM_BYTES, stream>>>(
            x, W1, b1, be1, W2, b2, be2, W3, b3, be3, W4, b4,
            W1p, W2p, W3p, W4p, out);
    } else {
        (void)hipFuncSetAttribute(reinterpret_cast<const void*>(mlp_fused<false>),
                                  hipFuncAttributeMaxDynamicSharedMemorySize, (int)SMEM_BYTES);
        mlp_fused<false><<<grid, blk, SMEM_BYTES, stream>>>(
            x, W1, b1, be1, W2, b2, be2, W3, b3, be3, W4, b4,
            nullptr, nullptr, nullptr, nullptr, out);
    }
}

// Round 3
// 208.722 us; speedup vs baseline: 2.4948x; 1.0474x over previous
//
#include <hip/hip_runtime.h>
#include <stdint.h>

#define G_ 8
#define S_ 16
#define H_ 512
#define TB 64
#define NTH 512

typedef _Float16 h16;
typedef _Float16 h16x8 __attribute__((ext_vector_type(8)));
typedef float f32x4 __attribute__((ext_vector_type(4)));

#define XB_STRIDE 40                      // h16 units per xb row (80 B, bank-spread)
#define HB_BYTES (TB * 1024)              // 64 rows x 512 h16 = 64 KB
#define SMEM_BYTES (HB_BYTES + TB * XB_STRIDE * 2)   // ~69 KB -> 2 blocks/CU

__device__ __forceinline__ float swishf(float v, float sp) {
    const float e = __expf(-v * sp);
    return v * __builtin_amdgcn_rcpf(1.0f + e) * (1.0f / 1.1f);
}

// swizzled byte offset into hbuf: row stride 1024B, XOR bits 4-6 with row&7
__device__ __forceinline__ uint32_t hswz(int row, uint32_t byte_in_row) {
    return (uint32_t)row * 1024u + (byte_in_row ^ (((uint32_t)(row & 7)) << 4));
}

// B fragment: packed layout [colBlk][kBlk=K/32][64 lanes][8 h16] -> one coalesced 16B/lane read.
// Fallback (USEWS=false): gather from fp32 row-major W[N][Ksrc]; k >= Ksrc reads 0 (W1 pad).
template<bool USEWS>
__device__ __forceinline__ h16x8 loadBfrag(const h16* __restrict__ wpk,
                                           const float* __restrict__ wf,
                                           int colBlk, int k0, int ln, int K, int Ksrc) {
    if constexpr (USEWS) {
        return *(const h16x8*)(wpk + ((size_t)colBlk * (K >> 5) + (k0 >> 5)) * 512 + ln * 8);
    } else {
        const int row = colBlk * 16 + (ln & 15);
        const int k = k0 + (ln >> 4) * 8;
        h16x8 r;
        if (k < Ksrc) {
            const float* p = wf + (size_t)row * Ksrc + k;
            #pragma unroll
            for (int j = 0; j < 8; ++j) r[j] = (h16)p[j];
        } else {
            #pragma unroll
            for (int j = 0; j < 8; ++j) r[j] = (h16)0.f;
        }
        return r;
    }
}

// swish + bias, then pack pairs of adjacent cols via shfl_xor(1) -> ds_write_b32
__device__ __forceinline__ void swish_store(const f32x4 (&acc)[4][4], char* hb,
                                            const float* __restrict__ bias, float sp,
                                            int wc0, int ln) {
    const int l15 = ln & 15, lq = ln >> 4, pe = l15 & 1;
    #pragma unroll
    for (int nt = 0; nt < 4; ++nt) {
        const int col = wc0 + nt * 16 + l15;
        const float bv = bias[col];
        const uint32_t cb2 = (uint32_t)((col & ~1) * 2);   // byte offset of even col of pair
        #pragma unroll
        for (int mt = 0; mt < 4; ++mt) {
            float v[4], t[4];
            #pragma unroll
            for (int r = 0; r < 4; ++r) v[r] = swishf(acc[mt][nt][r] + bv, sp);
            #pragma unroll
            for (int r = 0; r < 4; ++r) t[r] = __shfl_xor(v[r], 1);
            const int rowb = mt * 16 + lq * 4 + 2 * pe;
            #pragma unroll
            for (int q = 0; q < 2; ++q) {
                const float a0 = pe ? t[2 + q] : v[q];     // even col value, row rowb+q
                const float a1 = pe ? v[2 + q] : t[q];     // odd col value
                union { h16 h[2]; uint32_t u; } pk;
                pk.h[0] = (h16)a0; pk.h[1] = (h16)a1;
                *(uint32_t*)(hb + hswz(rowb + q, cb2)) = pk.u;
            }
        }
    }
}

// One H->H layer: wave computes 64x64 tile, K=512, B direct from global (packed frags)
template<bool USEWS>
__device__ __forceinline__ void layerH(f32x4 (&acc)[4][4],
                                       const h16* __restrict__ wpk, const float* __restrict__ wf,
                                       const char* __restrict__ hb, int wc0, int ln) {
    const int l15 = ln & 15, lq = ln >> 4;
    const int cB = wc0 >> 4;
    #pragma unroll
    for (int mt = 0; mt < 4; ++mt)
        #pragma unroll
        for (int nt = 0; nt < 4; ++nt) acc[mt][nt] = (f32x4){0.f, 0.f, 0.f, 0.f};

    h16x8 bfr[4];
    #pragma unroll
    for (int nt = 0; nt < 4; ++nt)
        bfr[nt] = loadBfrag<USEWS>(wpk, wf, cB + nt, 0, ln, H_, H_);

    #pragma unroll 2
    for (int k0 = 0; k0 < H_; k0 += 32) {
        h16x8 bnx[4];
        const int kn = (k0 + 32 < H_) ? (k0 + 32) : 0;   // clamped prefetch (last iter dummy)
        #pragma unroll
        for (int nt = 0; nt < 4; ++nt)
            bnx[nt] = loadBfrag<USEWS>(wpk, wf, cB + nt, kn, ln, H_, H_);
        #pragma unroll
        for (int mt = 0; mt < 4; ++mt) {
            const h16x8 a = *(const h16x8*)(hb + hswz(mt * 16 + l15,
                                                      (uint32_t)(k0 * 2 + lq * 16)));
            #pragma unroll
            for (int nt = 0; nt < 4; ++nt)
                acc[mt][nt] = __builtin_amdgcn_mfma_f32_16x16x32_f16(a, bfr[nt], acc[mt][nt], 0, 0, 0);
        }
        #pragma unroll
        for (int nt = 0; nt < 4; ++nt) bfr[nt] = bnx[nt];
    }
}

template<bool USEWS>
__global__ __launch_bounds__(NTH, 4) void mlp_fused(
    const float* __restrict__ x,
    const float* __restrict__ W1f, const float* __restrict__ b1, const float* __restrict__ be1,
    const float* __restrict__ W2f, const float* __restrict__ b2, const float* __restrict__ be2,
    const float* __restrict__ W3f, const float* __restrict__ b3, const float* __restrict__ be3,
    const float* __restrict__ W4f, const float* __restrict__ b4,
    const h16* __restrict__ W1p, const h16* __restrict__ W2p,
    const h16* __restrict__ W3p, const h16* __restrict__ W4p,
    float* __restrict__ out) {
    extern __shared__ char smem[];
    h16* __restrict__ xb = (h16*)(smem + HB_BYTES);

    const int bid = blockIdx.x;
    const int g = bid & 7;                 // group == XCD; co-resident blocks share weights in L2
    const int rowbase = (bid >> 3) * TB;
    const int tid = threadIdx.x;
    const int wv = tid >> 6;
    const int ln = tid & 63;
    const int l15 = ln & 15;
    const int lq = ln >> 4;
    const int wc0 = wv * 64;               // 8 waves x 64-col slices over [64][512]

    const float sp1 = log1pf(__expf(be1[g]));
    const float sp2 = log1pf(__expf(be2[g]));
    const float sp3 = log1pf(__expf(be3[g]));

    const h16* w1p = W1p + (size_t)g * H_ * 32;
    const h16* w2p = W2p + (size_t)g * H_ * H_;
    const h16* w3p = W3p + (size_t)g * H_ * H_;
    const h16* w4p = W4p + (size_t)g * S_ * H_;
    const float* w1f = W1f + (size_t)g * H_ * S_;
    const float* w2f = W2f + (size_t)g * H_ * H_;
    const float* w3f = W3f + (size_t)g * H_ * H_;
    const float* w4f = W4f + (size_t)g * S_ * H_;

    // stage x tile -> fp16, K padded 16->32 with zeros
    for (int i = tid; i < TB * S_; i += NTH) {
        const int r = i >> 4, s = i & 15;
        const float v = x[(size_t)(rowbase + r) * (G_ * S_) + g * S_ + s];
        xb[r * XB_STRIDE + s] = (h16)v;
        xb[r * XB_STRIDE + 16 + s] = (h16)0.f;
    }
    __syncthreads();

    f32x4 acc[4][4];

    // ---- layer 1: [64,16(->32)] x W1[512,16]^T, single K-step ----
    {
        #pragma unroll
        for (int mt = 0; mt < 4; ++mt)
            #pragma unroll
            for (int nt = 0; nt < 4; ++nt) acc[mt][nt] = (f32x4){0.f, 0.f, 0.f, 0.f};
        h16x8 bfr[4];
        #pragma unroll
        for (int nt = 0; nt < 4; ++nt)
            bfr[nt] = loadBfrag<USEWS>(w1p, w1f, (wc0 >> 4) + nt, 0, ln, 32, S_);
        #pragma unroll
        for (int mt = 0; mt < 4; ++mt) {
            const h16x8 a = *(const h16x8*)(xb + (mt * 16 + l15) * XB_STRIDE + lq * 8);
            #pragma unroll
            for (int nt = 0; nt < 4; ++nt)
                acc[mt][nt] = __builtin_amdgcn_mfma_f32_16x16x32_f16(a, bfr[nt], acc[mt][nt], 0, 0, 0);
        }
    }
    swish_store(acc, smem, b1 + g * H_, sp1, wc0, ln);
    __syncthreads();

    // ---- layer 2 ----
    layerH<USEWS>(acc, w2p, w2f, smem, wc0, ln);
    __syncthreads();                       // all hbuf reads done
    swish_store(acc, smem, b2 + g * H_, sp2, wc0, ln);
    __syncthreads();

    // ---- layer 3 ----
    layerH<USEWS>(acc, w3p, w3f, smem, wc0, ln);
    __syncthreads();
    swish_store(acc, smem, b3 + g * H_, sp3, wc0, ln);
    __syncthreads();

    // ---- layer 4: out[64,16] = h3 x W4[16,512]^T ; waves 0..3 own 16-row m-tiles ----
    if (wv < 4) {
        f32x4 a4 = {0.f, 0.f, 0.f, 0.f};
        #pragma unroll 2
        for (int k0 = 0; k0 < H_; k0 += 32) {
            const h16x8 a = *(const h16x8*)(smem + hswz(wv * 16 + l15,
                                                        (uint32_t)(k0 * 2 + lq * 16)));
            const h16x8 b = loadBfrag<USEWS>(w4p, w4f, 0, k0, ln, H_, H_);
            a4 = __builtin_amdgcn_mfma_f32_16x16x32_f16(a, b, a4, 0, 0, 0);
        }
        const float bv = b4[g * S_ + l15];
        #pragma unroll
        for (int r = 0; r < 4; ++r)
            out[(size_t)(rowbase + wv * 16 + lq * 4 + r) * (G_ * S_) + g * S_ + l15] = a4[r] + bv;
    }
}

// ---- weight repack: fp32 [N][Ks] -> fp16 MFMA-fragment blocks [N/16][Kd/32][64][8] ----
__global__ void packW(const float* __restrict__ s, h16* __restrict__ d,
                      int N, int Kd, int Ks) {
    const int t = blockIdx.x * 256 + threadIdx.x;
    const int total = (N * Kd) >> 3;
    if (t >= total) return;
    const int ln = t & 63;
    const int blk = t >> 6;
    const int kblocks = Kd >> 5;
    const int kb = blk % kblocks;
    const int nb = blk / kblocks;
    const int row = nb * 16 + (ln & 15);
    const int k = kb * 32 + (ln >> 4) * 8;
    h16x8 o;
    #pragma unroll
    for (int j = 0; j < 8; ++j)
        o[j] = (h16)((k + j < Ks) ? s[(size_t)row * Ks + k + j] : 0.f);
    *(h16x8*)(d + (size_t)t * 8) = o;
}

extern "C" void kernel_launch(void* const* d_in, const int* in_sizes, int n_in,
                              void* d_out, int out_size, void* d_ws, size_t ws_size,
                              hipStream_t stream) {
    const float* x   = (const float*)d_in[0];
    const float* W1  = (const float*)d_in[1];
    const float* b1  = (const float*)d_in[2];
    const float* be1 = (const float*)d_in[3];
    const float* W2  = (const float*)d_in[4];
    const float* b2  = (const float*)d_in[5];
    const float* be2 = (const float*)d_in[6];
    const float* W3  = (const float*)d_in[7];
    const float* b3  = (const float*)d_in[8];
    const float* be3 = (const float*)d_in[9];
    const float* W4  = (const float*)d_in[10];
    const float* b4  = (const float*)d_in[11];
    float* out = (float*)d_out;

    const size_t nW2  = (size_t)G_ * H_ * H_;   // 2097152
    const size_t nW1p = (size_t)G_ * H_ * 32;   // 131072 (K padded 16->32)
    const size_t nW4  = (size_t)G_ * S_ * H_;   // 65536
    const size_t need = (2 * nW2 + nW1p + nW4) * sizeof(h16);

    const dim3 grid(2048), blk(NTH);            // (16384/TB) * G_

    if (ws_size >= need) {
        h16* W2p = (h16*)d_ws;
        h16* W3p = W2p + nW2;
        h16* W1p = W3p + nW2;
        h16* W4p = W1p + nW1p;
        packW<<<dim3((unsigned)((nW2 / 8 + 255) / 256)), dim3(256), 0, stream>>>(W2, W2p, G_ * H_, H_, H_);
        packW<<<dim3((unsigned)((nW2 / 8 + 255) / 256)), dim3(256), 0, stream>>>(W3, W3p, G_ * H_, H_, H_);
        packW<<<dim3((unsigned)((nW4 / 8 + 255) / 256)), dim3(256), 0, stream>>>(W4, W4p, G_ * S_, H_, H_);
        packW<<<dim3((unsigned)((nW1p / 8 + 255) / 256)), dim3(256), 0, stream>>>(W1, W1p, G_ * H_, 32, S_);
        (void)hipFuncSetAttribute(reinterpret_cast<const void*>(mlp_fused<true>),
                                  hipFuncAttributeMaxDynamicSharedMemorySize, (int)SMEM_BYTES);
        mlp_fused<true><<<grid, blk, SMEM_BYTES, stream>>>(
            x, W1, b1, be1, W2, b2, be2, W3, b3, be3, W4, b4,
            W1p, W2p, W3p, W4p, out);
    } else {
        (void)hipFuncSetAttribute(reinterpret_cast<const void*>(mlp_fused<false>),
                                  hipFuncAttributeMaxDynamicSharedMemorySize, (int)SMEM_BYTES);
        mlp_fused<false><<<grid, blk, SMEM_BYTES, stream>>>(
            x, W1, b1, be1, W2, b2, be2, W3, b3, be3, W4, b4,
            nullptr, nullptr, nullptr, nullptr, out);
    }
}

// Round 5
// 205.873 us; speedup vs baseline: 2.5294x; 1.0138x over previous
//
#include <hip/hip_runtime.h>
#include <stdint.h>

#define G_ 8
#define S_ 16
#define H_ 512
#define TB 64
#define NTH 512

typedef _Float16 h16;
typedef _Float16 h16x8 __attribute__((ext_vector_type(8)));
typedef float f32x4 __attribute__((ext_vector_type(4)));
typedef float f32x16 __attribute__((ext_vector_type(16)));

#define XB_STRIDE 24                      // h16 units per xb row (48 B)
#define HB_BYTES (TB * 1024)              // 64 rows x 512 h16 = 64 KB
#define SMEM_BYTES (HB_BYTES + TB * XB_STRIDE * 2)   // ~67 KB -> 2 blocks/CU

__device__ __forceinline__ float swishf(float v, float sp) {
    const float e = __expf(-v * sp);
    return v * __builtin_amdgcn_rcpf(1.0f + e) * (1.0f / 1.1f);
}

// pack two f32 -> one u32 of 2x fp16 (RTZ)
__device__ __forceinline__ uint32_t pk16(float a, float b) {
    return __builtin_bit_cast(uint32_t, __builtin_amdgcn_cvt_pkrtz(a, b));
}

// swizzled byte offset into hbuf: row stride 1024B, XOR bits 4-6 with row&7
__device__ __forceinline__ uint32_t hswz(int row, uint32_t byte_in_row) {
    return (uint32_t)row * 1024u + (byte_in_row ^ (((uint32_t)(row & 7)) << 4));
}

// ---- A-operand (weight) fragment loaders ----
// 32x32x16 frag: lane ln: m-row = nb*32 + (ln&31), k = ks*16 + (ln>>5)*8 + j
// packed layout: [nb][ks][64][8] contiguous -> one dwordx4 per lane.
template<bool USEWS>
__device__ __forceinline__ h16x8 loadA32(const h16* __restrict__ wpk,
                                         const float* __restrict__ wf,
                                         int nb, int ks, int ln, int KB, int Ksrc) {
    if constexpr (USEWS) {
        return *(const h16x8*)(wpk + (((size_t)nb * KB + ks) * 64 + ln) * 8);
    } else {
        const int row = nb * 32 + (ln & 31);
        const int k = ks * 16 + (ln >> 5) * 8;
        const float* p = wf + (size_t)row * Ksrc + k;
        h16x8 r;
        #pragma unroll
        for (int j = 0; j < 8; ++j) r[j] = (h16)p[j];
        return r;
    }
}

// 16x16x32 frag (W4): lane ln: m-row = ln&15, k = ks32*32 + (ln>>4)*8 + j
template<bool USEWS>
__device__ __forceinline__ h16x8 loadA16(const h16* __restrict__ wpk,
                                         const float* __restrict__ wf,
                                         int ks32, int ln, int Ksrc) {
    if constexpr (USEWS) {
        return *(const h16x8*)(wpk + ((size_t)ks32 * 64 + ln) * 8);
    } else {
        const int row = ln & 15;
        const int k = ks32 * 32 + (ln >> 4) * 8;
        const float* p = wf + (size_t)row * Ksrc + k;
        h16x8 r;
        #pragma unroll
        for (int j = 0; j < 8; ++j) r[j] = (h16)p[j];
        return r;
    }
}

// D (32x32): col = lane&31 = batch-row b; row = (reg&3) + 8*(reg>>2) + 4*(lane>>5) = out-chan o.
// Lane holds 4 CONSECUTIVE o per reg-quad -> cvt_pkrtz x2 -> one ds_write_b64.
__device__ __forceinline__ void swish_store32(const f32x16 (&acc)[2][2], char* hb,
                                              const float* __restrict__ bias, float sp,
                                              int wc0, int ln) {
    const int l31 = ln & 31, lh = ln >> 5;
    #pragma unroll
    for (int ot = 0; ot < 2; ++ot) {
        #pragma unroll
        for (int rq = 0; rq < 4; ++rq) {
            const int col0 = wc0 + ot * 32 + rq * 8 + lh * 4;
            const f32x4 bv = *(const f32x4*)(bias + col0);
            #pragma unroll
            for (int bt = 0; bt < 2; ++bt) {
                const int b = bt * 32 + l31;
                const float v0 = swishf(acc[ot][bt][rq * 4 + 0] + bv[0], sp);
                const float v1 = swishf(acc[ot][bt][rq * 4 + 1] + bv[1], sp);
                const float v2 = swishf(acc[ot][bt][rq * 4 + 2] + bv[2], sp);
                const float v3 = swishf(acc[ot][bt][rq * 4 + 3] + bv[3], sp);
                const uint64_t u = (uint64_t)pk16(v0, v1)
                                 | ((uint64_t)pk16(v2, v3) << 32);
                *(uint64_t*)(hb + hswz(b, (uint32_t)(col0 * 2))) = u;
            }
        }
    }
}

// One H->H layer: wave tile 64 o-cols x 64 b-rows, 32x32x16 MFMA, K=512.
// A = weights (global, depth-2 prefetch), B = activations (LDS, depth-1).
template<bool USEWS>
__device__ __forceinline__ void layerH32(f32x16 (&acc)[2][2],
                                         const h16* __restrict__ wpk, const float* __restrict__ wf,
                                         const char* __restrict__ hb, int wc0, int ln) {
    const int l31 = ln & 31, lh = ln >> 5;
    const int cB = wc0 >> 5;
    #pragma unroll
    for (int ot = 0; ot < 2; ++ot)
        #pragma unroll
        for (int bt = 0; bt < 2; ++bt) acc[ot][bt] = (f32x16)(0.f);

    h16x8 aC[2], aN[2], bC[2];
    #pragma unroll
    for (int ot = 0; ot < 2; ++ot) {
        aC[ot] = loadA32<USEWS>(wpk, wf, cB + ot, 0, ln, 32, H_);
        aN[ot] = loadA32<USEWS>(wpk, wf, cB + ot, 1, ln, 32, H_);
    }
    #pragma unroll
    for (int bt = 0; bt < 2; ++bt)
        bC[bt] = *(const h16x8*)(hb + hswz(bt * 32 + l31, (uint32_t)(lh * 16)));

    #pragma unroll 4
    for (int ks = 0; ks < 32; ++ks) {
        h16x8 aF[2], bN[2];
        const int ksA = (ks + 2 < 32) ? ks + 2 : 0;   // clamped dummy prefetch at tail
        const int ksB = (ks + 1 < 32) ? ks + 1 : 0;
        #pragma unroll
        for (int ot = 0; ot < 2; ++ot)
            aF[ot] = loadA32<USEWS>(wpk, wf, cB + ot, ksA, ln, 32, H_);
        #pragma unroll
        for (int bt = 0; bt < 2; ++bt)
            bN[bt] = *(const h16x8*)(hb + hswz(bt * 32 + l31,
                                               (uint32_t)(ksB * 32 + lh * 16)));
        __builtin_amdgcn_s_setprio(1);
        #pragma unroll
        for (int ot = 0; ot < 2; ++ot)
            #pragma unroll
            for (int bt = 0; bt < 2; ++bt)
                acc[ot][bt] = __builtin_amdgcn_mfma_f32_32x32x16_f16(aC[ot], bC[bt],
                                                                     acc[ot][bt], 0, 0, 0);
        __builtin_amdgcn_s_setprio(0);
        #pragma unroll
        for (int ot = 0; ot < 2; ++ot) { aC[ot] = aN[ot]; aN[ot] = aF[ot]; }
        #pragma unroll
        for (int bt = 0; bt < 2; ++bt) bC[bt] = bN[bt];
    }
}

template<bool USEWS>
__global__ __launch_bounds__(NTH, 4) void mlp_fused(
    const float* __restrict__ x,
    const float* __restrict__ W1f, const float* __restrict__ b1, const float* __restrict__ be1,
    const float* __restrict__ W2f, const float* __restrict__ b2, const float* __restrict__ be2,
    const float* __restrict__ W3f, const float* __restrict__ b3, const float* __restrict__ be3,
    const float* __restrict__ W4f, const float* __restrict__ b4,
    const h16* __restrict__ W1p, const h16* __restrict__ W2p,
    const h16* __restrict__ W3p, const h16* __restrict__ W4p,
    float* __restrict__ out) {
    extern __shared__ char smem[];
    h16* __restrict__ xb = (h16*)(smem + HB_BYTES);

    const int bid = blockIdx.x;
    const int g = bid & 7;                 // group == XCD; co-resident blocks share weights in L2
    const int rowbase = (bid >> 3) * TB;
    const int tid = threadIdx.x;
    const int wv = tid >> 6;
    const int ln = tid & 63;
    const int l31 = ln & 31;
    const int lh = ln >> 5;
    const int wc0 = wv * 64;               // 8 waves x 64-col slices over [64 rows][512 cols]

    const float sp1 = log1pf(__expf(be1[g]));
    const float sp2 = log1pf(__expf(be2[g]));
    const float sp3 = log1pf(__expf(be3[g]));

    const h16* w1p = W1p + (size_t)g * H_ * S_;
    const h16* w2p = W2p + (size_t)g * H_ * H_;
    const h16* w3p = W3p + (size_t)g * H_ * H_;
    const h16* w4p = W4p + (size_t)g * S_ * H_;
    const float* w1f = W1f + (size_t)g * H_ * S_;
    const float* w2f = W2f + (size_t)g * H_ * H_;
    const float* w3f = W3f + (size_t)g * H_ * H_;
    const float* w4f = W4f + (size_t)g * S_ * H_;

    // stage x tile -> fp16 (K=16 exact for 32x32x16, no padding)
    {
        const int idx = tid * 2;                         // 64*16 = 1024 h16, 2 per thread
        const int r = idx >> 4, s = idx & 15;
        const float2 v = *(const float2*)(x + (size_t)(rowbase + r) * (G_ * S_) + g * S_ + s);
        *(uint32_t*)((char*)xb + (r * XB_STRIDE + s) * 2) = pk16(v.x, v.y);
    }
    __syncthreads();

    f32x16 acc[2][2];

    // ---- layer 1: A=W1[512,16] frags, B=x frags, single K-step ----
    {
        #pragma unroll
        for (int ot = 0; ot < 2; ++ot)
            #pragma unroll
            for (int bt = 0; bt < 2; ++bt) acc[ot][bt] = (f32x16)(0.f);
        h16x8 aW[2], bX[2];
        #pragma unroll
        for (int ot = 0; ot < 2; ++ot)
            aW[ot] = loadA32<USEWS>(w1p, w1f, (wc0 >> 5) + ot, 0, ln, 1, S_);
        #pragma unroll
        for (int bt = 0; bt < 2; ++bt)
            bX[bt] = *(const h16x8*)(xb + (bt * 32 + l31) * XB_STRIDE + lh * 8);
        #pragma unroll
        for (int ot = 0; ot < 2; ++ot)
            #pragma unroll
            for (int bt = 0; bt < 2; ++bt)
                acc[ot][bt] = __builtin_amdgcn_mfma_f32_32x32x16_f16(aW[ot], bX[bt],
                                                                     acc[ot][bt], 0, 0, 0);
    }
    swish_store32(acc, smem, b1 + g * H_, sp1, wc0, ln);
    __syncthreads();

    // ---- layer 2 ----
    layerH32<USEWS>(acc, w2p, w2f, smem, wc0, ln);
    __syncthreads();                       // all hbuf reads done
    swish_store32(acc, smem, b2 + g * H_, sp2, wc0, ln);
    __syncthreads();

    // ---- layer 3 ----
    layerH32<USEWS>(acc, w3p, w3f, smem, wc0, ln);
    __syncthreads();
    swish_store32(acc, smem, b3 + g * H_, sp3, wc0, ln);
    __syncthreads();

    // ---- layer 4: A=W4[16,512] frags (16x16x32), B=act; D: col=b, rows=4 consec s ----
    if (wv < 4) {
        f32x4 a4 = {0.f, 0.f, 0.f, 0.f};
        const int l15 = ln & 15, lq = ln >> 4;
        #pragma unroll 4
        for (int ks = 0; ks < 16; ++ks) {
            const h16x8 a = loadA16<USEWS>(w4p, w4f, ks, ln, H_);
            const h16x8 b = *(const h16x8*)(smem + hswz(wv * 16 + l15,
                                                        (uint32_t)(ks * 64 + lq * 16)));
            a4 = __builtin_amdgcn_mfma_f32_16x16x32_f16(a, b, a4, 0, 0, 0);
        }
        const int brow = wv * 16 + l15;    // batch row
        const int s0 = lq * 4;             // 4 consecutive state channels
        const f32x4 bv = *(const f32x4*)(b4 + g * S_ + s0);
        f32x4 o4;
        #pragma unroll
        for (int r = 0; r < 4; ++r) o4[r] = a4[r] + bv[r];
        *(f32x4*)(out + (size_t)(rowbase + brow) * (G_ * S_) + g * S_ + s0) = o4;
    }
}

// ---- weight repack (32x32x16 shape): fp32 [Ntot][Ks] -> [nb][kb][64][8] frags ----
__global__ void packW32(const float* __restrict__ s, h16* __restrict__ d,
                        int NB_total, int KB, int Ks) {
    const int t = blockIdx.x * 256 + threadIdx.x;
    const int total = NB_total * KB * 64;
    if (t >= total) return;
    const int ln = t & 63;
    const int blk = t >> 6;
    const int kb = blk % KB;
    const int nbg = blk / KB;
    const int row = nbg * 32 + (ln & 31);
    const int k = kb * 16 + (ln >> 5) * 8;
    const float* p = s + (size_t)row * Ks + k;
    h16x8 o;
    #pragma unroll
    for (int j = 0; j < 8; ++j) o[j] = (h16)p[j];
    *(h16x8*)(d + (size_t)t * 8) = o;
}

// ---- weight repack (16x16x32 shape, W4): fp32 [Ntot=G*16][512] -> [nb][kb][64][8] ----
__global__ void packW16(const float* __restrict__ s, h16* __restrict__ d,
                        int NB_total, int KB, int Ks) {
    const int t = blockIdx.x * 256 + threadIdx.x;
    const int total = NB_total * KB * 64;
    if (t >= total) return;
    const int ln = t & 63;
    const int blk = t >> 6;
    const int kb = blk % KB;
    const int nbg = blk / KB;
    const int row = nbg * 16 + (ln & 15);
    const int k = kb * 32 + (ln >> 4) * 8;
    const float* p = s + (size_t)row * Ks + k;
    h16x8 o;
    #pragma unroll
    for (int j = 0; j < 8; ++j) o[j] = (h16)p[j];
    *(h16x8*)(d + (size_t)t * 8) = o;
}

extern "C" void kernel_launch(void* const* d_in, const int* in_sizes, int n_in,
                              void* d_out, int out_size, void* d_ws, size_t ws_size,
                              hipStream_t stream) {
    const float* x   = (const float*)d_in[0];
    const float* W1  = (const float*)d_in[1];
    const float* b1  = (const float*)d_in[2];
    const float* be1 = (const float*)d_in[3];
    const float* W2  = (const float*)d_in[4];
    const float* b2  = (const float*)d_in[5];
    const float* be2 = (const float*)d_in[6];
    const float* W3  = (const float*)d_in[7];
    const float* b3  = (const float*)d_in[8];
    const float* be3 = (const float*)d_in[9];
    const float* W4  = (const float*)d_in[10];
    const float* b4  = (const float*)d_in[11];
    float* out = (float*)d_out;

    const size_t nW2  = (size_t)G_ * H_ * H_;   // 2097152
    const size_t nW1p = (size_t)G_ * H_ * S_;   // 65536
    const size_t nW4  = (size_t)G_ * S_ * H_;   // 65536
    const size_t need = (2 * nW2 + nW1p + nW4) * sizeof(h16);

    const dim3 grid(2048), blk(NTH);            // (16384/TB) * G_

    if (ws_size >= need) {
        h16* W2p = (h16*)d_ws;
        h16* W3p = W2p + nW2;
        h16* W1p = W3p + nW2;
        h16* W4p = W1p + nW1p;
        // W2/W3: NB_total = G*16 (32-row blocks), KB = 32 (16-k blocks), Ks = 512
        packW32<<<dim3((unsigned)((nW2 / 8 + 255) / 256)), dim3(256), 0, stream>>>(W2, W2p, G_ * 16, 32, H_);
        packW32<<<dim3((unsigned)((nW2 / 8 + 255) / 256)), dim3(256), 0, stream>>>(W3, W3p, G_ * 16, 32, H_);
        // W1: NB_total = G*16, KB = 1, Ks = 16
        packW32<<<dim3((unsigned)((nW1p / 8 + 255) / 256)), dim3(256), 0, stream>>>(W1, W1p, G_ * 16, 1, S_);
        // W4: 16x16x32 shape: NB_total = G (16-row blocks), KB = 16, Ks = 512
        packW16<<<dim3((unsigned)((nW4 / 8 + 255) / 256)), dim3(256), 0, stream>>>(W4, W4p, G_, 16, H_);
        (void)hipFuncSetAttribute(reinterpret_cast<const void*>(mlp_fused<true>),
                                  hipFuncAttributeMaxDynamicSharedMemorySize, (int)SMEM_BYTES);
        mlp_fused<true><<<grid, blk, SMEM_BYTES, stream>>>(
            x, W1, b1, be1, W2, b2, be2, W3, b3, be3, W4, b4,
            W1p, W2p, W3p, W4p, out);
    } else {
        (void)hipFuncSetAttribute(reinterpret_cast<const void*>(mlp_fused<false>),
                                  hipFuncAttributeMaxDynamicSharedMemorySize, (int)SMEM_BYTES);
        mlp_fused<false><<<grid, blk, SMEM_BYTES, stream>>>(
            x, W1, b1, be1, W2, b2, be2, W3, b3, be3, W4, b4,
            nullptr, nullptr, nullptr, nullptr, out);
    }
}

// Round 6
// 200.020 us; speedup vs baseline: 2.6034x; 1.0293x over previous
//
#include <hip/hip_runtime.h>
#include <stdint.h>

#define G_ 8
#define S_ 16
#define H_ 512
#define TB 64
#define NTH 512

typedef _Float16 h16;
typedef _Float16 h16x8 __attribute__((ext_vector_type(8)));
typedef float f32x4 __attribute__((ext_vector_type(4)));
typedef float f32x16 __attribute__((ext_vector_type(16)));

#define XB_STRIDE 24                      // h16 units per xb row (48 B)
#define HB_BYTES (TB * 1024)              // 64 rows x 512 h16 = 64 KB
#define SMEM_BYTES (HB_BYTES + TB * XB_STRIDE * 2)   // ~67 KB -> 2 blocks/CU

__device__ __forceinline__ float swishf(float v, float sp) {
    const float e = __expf(-v * sp);
    return v * __builtin_amdgcn_rcpf(1.0f + e) * (1.0f / 1.1f);
}

// pack two f32 -> one u32 of 2x fp16 (RTZ)
__device__ __forceinline__ uint32_t pk16(float a, float b) {
    return __builtin_bit_cast(uint32_t, __builtin_amdgcn_cvt_pkrtz(a, b));
}

// swizzled byte offset into hbuf: row stride 1024B, XOR bits 4-6 with row&7
__device__ __forceinline__ uint32_t hswz(int row, uint32_t byte_in_row) {
    return (uint32_t)row * 1024u + (byte_in_row ^ (((uint32_t)(row & 7)) << 4));
}

// ---- A-operand (weight) fragment loaders ----
// 32x32x16 frag: lane ln: m-row = nb*32 + (ln&31), k = ks*16 + (ln>>5)*8 + j
// packed layout: [nb][ks][64][8] contiguous -> one dwordx4 per lane.
template<bool USEWS>
__device__ __forceinline__ h16x8 loadA32(const h16* __restrict__ wpk,
                                         const float* __restrict__ wf,
                                         int nb, int ks, int ln, int KB, int Ksrc) {
    if constexpr (USEWS) {
        return *(const h16x8*)(wpk + (((size_t)nb * KB + ks) * 64 + ln) * 8);
    } else {
        const int row = nb * 32 + (ln & 31);
        const int k = ks * 16 + (ln >> 5) * 8;
        const float* p = wf + (size_t)row * Ksrc + k;
        h16x8 r;
        #pragma unroll
        for (int j = 0; j < 8; ++j) r[j] = (h16)p[j];
        return r;
    }
}

// 16x16x32 frag (W4): lane ln: m-row = ln&15, k = ks32*32 + (ln>>4)*8 + j
template<bool USEWS>
__device__ __forceinline__ h16x8 loadA16(const h16* __restrict__ wpk,
                                         const float* __restrict__ wf,
                                         int ks32, int ln, int Ksrc) {
    if constexpr (USEWS) {
        return *(const h16x8*)(wpk + ((size_t)ks32 * 64 + ln) * 8);
    } else {
        const int row = ln & 15;
        const int k = ks32 * 32 + (ln >> 4) * 8;
        const float* p = wf + (size_t)row * Ksrc + k;
        h16x8 r;
        #pragma unroll
        for (int j = 0; j < 8; ++j) r[j] = (h16)p[j];
        return r;
    }
}

// D (32x32): col = lane&31 = batch-row b; row = (reg&3) + 8*(reg>>2) + 4*(lane>>5) = out-chan o.
// Lane holds 4 CONSECUTIVE o per reg-quad -> cvt_pkrtz x2 -> one ds_write_b64.
__device__ __forceinline__ void swish_store32(const f32x16 (&acc)[2][2], char* hb,
                                              const float* __restrict__ bias, float sp,
                                              int wc0, int ln) {
    const int l31 = ln & 31, lh = ln >> 5;
    #pragma unroll
    for (int ot = 0; ot < 2; ++ot) {
        #pragma unroll
        for (int rq = 0; rq < 4; ++rq) {
            const int col0 = wc0 + ot * 32 + rq * 8 + lh * 4;
            const f32x4 bv = *(const f32x4*)(bias + col0);
            #pragma unroll
            for (int bt = 0; bt < 2; ++bt) {
                const int b = bt * 32 + l31;
                const float v0 = swishf(acc[ot][bt][rq * 4 + 0] + bv[0], sp);
                const float v1 = swishf(acc[ot][bt][rq * 4 + 1] + bv[1], sp);
                const float v2 = swishf(acc[ot][bt][rq * 4 + 2] + bv[2], sp);
                const float v3 = swishf(acc[ot][bt][rq * 4 + 3] + bv[3], sp);
                const uint64_t u = (uint64_t)pk16(v0, v1)
                                 | ((uint64_t)pk16(v2, v3) << 32);
                *(uint64_t*)(hb + hswz(b, (uint32_t)(col0 * 2))) = u;
            }
        }
    }
}

// One H->H layer: wave tile 64 o-cols x 64 b-rows, 32x32x16 MFMA, K=512.
// A = weights (global/L2), B = activations (LDS). NO hand pipelining:
// loads issued in-loop; the unroll-4 body gives the scheduler a window to
// software-pipeline WITHIN the 128-reg cap (hand dbuf overflowed it -> spill).
template<bool USEWS>
__device__ __forceinline__ void layerH32(f32x16 (&acc)[2][2],
                                         const h16* __restrict__ wpk, const float* __restrict__ wf,
                                         const char* __restrict__ hb, int wc0, int ln) {
    const int l31 = ln & 31, lh = ln >> 5;
    const int cB = wc0 >> 5;
    #pragma unroll
    for (int ot = 0; ot < 2; ++ot)
        #pragma unroll
        for (int bt = 0; bt < 2; ++bt) acc[ot][bt] = (f32x16)(0.f);

    #pragma unroll 4
    for (int ks = 0; ks < 32; ++ks) {
        const h16x8 a0 = loadA32<USEWS>(wpk, wf, cB + 0, ks, ln, 32, H_);
        const h16x8 a1 = loadA32<USEWS>(wpk, wf, cB + 1, ks, ln, 32, H_);
        const h16x8 b0 = *(const h16x8*)(hb + hswz(l31,      (uint32_t)(ks * 32 + lh * 16)));
        const h16x8 b1 = *(const h16x8*)(hb + hswz(32 + l31, (uint32_t)(ks * 32 + lh * 16)));
        __builtin_amdgcn_s_setprio(1);
        acc[0][0] = __builtin_amdgcn_mfma_f32_32x32x16_f16(a0, b0, acc[0][0], 0, 0, 0);
        acc[0][1] = __builtin_amdgcn_mfma_f32_32x32x16_f16(a0, b1, acc[0][1], 0, 0, 0);
        acc[1][0] = __builtin_amdgcn_mfma_f32_32x32x16_f16(a1, b0, acc[1][0], 0, 0, 0);
        acc[1][1] = __builtin_amdgcn_mfma_f32_32x32x16_f16(a1, b1, acc[1][1], 0, 0, 0);
        __builtin_amdgcn_s_setprio(0);
    }
}

template<bool USEWS>
__global__ __launch_bounds__(NTH, 4) void mlp_fused(
    const float* __restrict__ x,
    const float* __restrict__ W1f, const float* __restrict__ b1, const float* __restrict__ be1,
    const float* __restrict__ W2f, const float* __restrict__ b2, const float* __restrict__ be2,
    const float* __restrict__ W3f, const float* __restrict__ b3, const float* __restrict__ be3,
    const float* __restrict__ W4f, const float* __restrict__ b4,
    const h16* __restrict__ W1p, const h16* __restrict__ W2p,
    const h16* __restrict__ W3p, const h16* __restrict__ W4p,
    float* __restrict__ out) {
    extern __shared__ char smem[];
    h16* __restrict__ xb = (h16*)(smem + HB_BYTES);

    const int bid = blockIdx.x;
    const int g = bid & 7;                 // group == XCD; co-resident blocks share weights in L2
    const int rowbase = (bid >> 3) * TB;
    const int tid = threadIdx.x;
    const int wv = tid >> 6;
    const int ln = tid & 63;
    const int l31 = ln & 31;
    const int lh = ln >> 5;
    const int wc0 = wv * 64;               // 8 waves x 64-col slices over [64 rows][512 cols]

    const float sp1 = log1pf(__expf(be1[g]));
    const float sp2 = log1pf(__expf(be2[g]));
    const float sp3 = log1pf(__expf(be3[g]));

    const h16* w1p = W1p + (size_t)g * H_ * S_;
    const h16* w2p = W2p + (size_t)g * H_ * H_;
    const h16* w3p = W3p + (size_t)g * H_ * H_;
    const h16* w4p = W4p + (size_t)g * S_ * H_;
    const float* w1f = W1f + (size_t)g * H_ * S_;
    const float* w2f = W2f + (size_t)g * H_ * H_;
    const float* w3f = W3f + (size_t)g * H_ * H_;
    const float* w4f = W4f + (size_t)g * S_ * H_;

    // stage x tile -> fp16 (K=16 exact for 32x32x16, no padding)
    {
        const int idx = tid * 2;                         // 64*16 = 1024 h16, 2 per thread
        const int r = idx >> 4, s = idx & 15;
        const float2 v = *(const float2*)(x + (size_t)(rowbase + r) * (G_ * S_) + g * S_ + s);
        *(uint32_t*)((char*)xb + (r * XB_STRIDE + s) * 2) = pk16(v.x, v.y);
    }
    __syncthreads();

    f32x16 acc[2][2];

    // ---- layer 1: A=W1[512,16] frags, B=x frags, single K-step ----
    {
        #pragma unroll
        for (int ot = 0; ot < 2; ++ot)
            #pragma unroll
            for (int bt = 0; bt < 2; ++bt) acc[ot][bt] = (f32x16)(0.f);
        h16x8 aW[2], bX[2];
        #pragma unroll
        for (int ot = 0; ot < 2; ++ot)
            aW[ot] = loadA32<USEWS>(w1p, w1f, (wc0 >> 5) + ot, 0, ln, 1, S_);
        #pragma unroll
        for (int bt = 0; bt < 2; ++bt)
            bX[bt] = *(const h16x8*)(xb + (bt * 32 + l31) * XB_STRIDE + lh * 8);
        #pragma unroll
        for (int ot = 0; ot < 2; ++ot)
            #pragma unroll
            for (int bt = 0; bt < 2; ++bt)
                acc[ot][bt] = __builtin_amdgcn_mfma_f32_32x32x16_f16(aW[ot], bX[bt],
                                                                     acc[ot][bt], 0, 0, 0);
    }
    swish_store32(acc, smem, b1 + g * H_, sp1, wc0, ln);
    __syncthreads();

    // ---- layer 2 ----
    layerH32<USEWS>(acc, w2p, w2f, smem, wc0, ln);
    __syncthreads();                       // all hbuf reads done
    swish_store32(acc, smem, b2 + g * H_, sp2, wc0, ln);
    __syncthreads();

    // ---- layer 3 ----
    layerH32<USEWS>(acc, w3p, w3f, smem, wc0, ln);
    __syncthreads();
    swish_store32(acc, smem, b3 + g * H_, sp3, wc0, ln);
    __syncthreads();

    // ---- layer 4: A=W4[16,512] frags (16x16x32), B=act; D: col=b, rows=4 consec s ----
    if (wv < 4) {
        f32x4 a4 = {0.f, 0.f, 0.f, 0.f};
        const int l15 = ln & 15, lq = ln >> 4;
        #pragma unroll 4
        for (int ks = 0; ks < 16; ++ks) {
            const h16x8 a = loadA16<USEWS>(w4p, w4f, ks, ln, H_);
            const h16x8 b = *(const h16x8*)(smem + hswz(wv * 16 + l15,
                                                        (uint32_t)(ks * 64 + lq * 16)));
            a4 = __builtin_amdgcn_mfma_f32_16x16x32_f16(a, b, a4, 0, 0, 0);
        }
        const int brow = wv * 16 + l15;    // batch row
        const int s0 = lq * 4;             // 4 consecutive state channels
        const f32x4 bv = *(const f32x4*)(b4 + g * S_ + s0);
        f32x4 o4;
        #pragma unroll
        for (int r = 0; r < 4; ++r) o4[r] = a4[r] + bv[r];
        *(f32x4*)(out + (size_t)(rowbase + brow) * (G_ * S_) + g * S_ + s0) = o4;
    }
}

// ---- weight repack (32x32x16 shape): fp32 [Ntot][Ks] -> [nb][kb][64][8] frags ----
__global__ void packW32(const float* __restrict__ s, h16* __restrict__ d,
                        int NB_total, int KB, int Ks) {
    const int t = blockIdx.x * 256 + threadIdx.x;
    const int total = NB_total * KB * 64;
    if (t >= total) return;
    const int ln = t & 63;
    const int blk = t >> 6;
    const int kb = blk % KB;
    const int nbg = blk / KB;
    const int row = nbg * 32 + (ln & 31);
    const int k = kb * 16 + (ln >> 5) * 8;
    const float* p = s + (size_t)row * Ks + k;
    h16x8 o;
    #pragma unroll
    for (int j = 0; j < 8; ++j) o[j] = (h16)p[j];
    *(h16x8*)(d + (size_t)t * 8) = o;
}

// ---- weight repack (16x16x32 shape, W4): fp32 [Ntot=G*16][512] -> [nb][kb][64][8] ----
__global__ void packW16(const float* __restrict__ s, h16* __restrict__ d,
                        int NB_total, int KB, int Ks) {
    const int t = blockIdx.x * 256 + threadIdx.x;
    const int total = NB_total * KB * 64;
    if (t >= total) return;
    const int ln = t & 63;
    const int blk = t >> 6;
    const int kb = blk % KB;
    const int nbg = blk / KB;
    const int row = nbg * 16 + (ln & 15);
    const int k = kb * 32 + (ln >> 4) * 8;
    const float* p = s + (size_t)row * Ks + k;
    h16x8 o;
    #pragma unroll
    for (int j = 0; j < 8; ++j) o[j] = (h16)p[j];
    *(h16x8*)(d + (size_t)t * 8) = o;
}

extern "C" void kernel_launch(void* const* d_in, const int* in_sizes, int n_in,
                              void* d_out, int out_size, void* d_ws, size_t ws_size,
                              hipStream_t stream) {
    const float* x   = (const float*)d_in[0];
    const float* W1  = (const float*)d_in[1];
    const float* b1  = (const float*)d_in[2];
    const float* be1 = (const float*)d_in[3];
    const float* W2  = (const float*)d_in[4];
    const float* b2  = (const float*)d_in[5];
    const float* be2 = (const float*)d_in[6];
    const float* W3  = (const float*)d_in[7];
    const float* b3  = (const float*)d_in[8];
    const float* be3 = (const float*)d_in[9];
    const float* W4  = (const float*)d_in[10];
    const float* b4  = (const float*)d_in[11];
    float* out = (float*)d_out;

    const size_t nW2  = (size_t)G_ * H_ * H_;   // 2097152
    const size_t nW1p = (size_t)G_ * H_ * S_;   // 65536
    const size_t nW4  = (size_t)G_ * S_ * H_;   // 65536
    const size_t need = (2 * nW2 + nW1p + nW4) * sizeof(h16);

    const dim3 grid(2048), blk(NTH);            // (16384/TB) * G_

    if (ws_size >= need) {
        h16* W2p = (h16*)d_ws;
        h16* W3p = W2p + nW2;
        h16* W1p = W3p + nW2;
        h16* W4p = W1p + nW1p;
        // W2/W3: NB_total = G*16 (32-row blocks), KB = 32 (16-k blocks), Ks = 512
        packW32<<<dim3((unsigned)((nW2 / 8 + 255) / 256)), dim3(256), 0, stream>>>(W2, W2p, G_ * 16, 32, H_);
        packW32<<<dim3((unsigned)((nW2 / 8 + 255) / 256)), dim3(256), 0, stream>>>(W3, W3p, G_ * 16, 32, H_);
        // W1: NB_total = G*16, KB = 1, Ks = 16
        packW32<<<dim3((unsigned)((nW1p / 8 + 255) / 256)), dim3(256), 0, stream>>>(W1, W1p, G_ * 16, 1, S_);
        // W4: 16x16x32 shape: NB_total = G (16-row blocks), KB = 16, Ks = 512
        packW16<<<dim3((unsigned)((nW4 / 8 + 255) / 256)), dim3(256), 0, stream>>>(W4, W4p, G_, 16, H_);
        (void)hipFuncSetAttribute(reinterpret_cast<const void*>(mlp_fused<true>),
                                  hipFuncAttributeMaxDynamicSharedMemorySize, (int)SMEM_BYTES);
        mlp_fused<true><<<grid, blk, SMEM_BYTES, stream>>>(
            x, W1, b1, be1, W2, b2, be2, W3, b3, be3, W4, b4,
            W1p, W2p, W3p, W4p, out);
    } else {
        (void)hipFuncSetAttribute(reinterpret_cast<const void*>(mlp_fused<false>),
                                  hipFuncAttributeMaxDynamicSharedMemorySize, (int)SMEM_BYTES);
        mlp_fused<false><<<grid, blk, SMEM_BYTES, stream>>>(
            x, W1, b1, be1, W2, b2, be2, W3, b3, be3, W4, b4,
            nullptr, nullptr, nullptr, nullptr, out);
    }
}